// Round 11
// baseline (202.014 us; speedup 1.0000x reference)
//
#include <hip/hip_runtime.h>

// Problem constants (fixed by the reference)
constexpr int N_NODES = 50000;
constexpr int E_EDGES = 400000;
constexpr int IN_DIM  = 128;
constexpr int HD      = 256;   // H*D
constexpr int H_HEADS = 8;
constexpr int D_HEAD  = 32;
constexpr int M_FEAT  = 8;
constexpr int K_NODES = N_NODES / H_HEADS;   // 6250 nodes need Phi
constexpr int CAP     = 48;    // bucket capacity; deg ~ Poisson(8), P(>=48) ~ 1e-23
constexpr int CSTRIDE = 16;    // ROUND-10 WIN: one counter per 64B line (main 71->55us;
                               // 16/line had ~128 serialized cross-XCD RMWs per hot line)
constexpr int BUCKET_BLOCKS = (E_EDGES + 255) / 256;   // 1563 (1 edge/thread)
constexpr int XFORM_BLOCKS  = (N_NODES + 63) / 64;     // 782 (64-row blocks)
constexpr int MAIN_BLOCKS   = XFORM_BLOCKS + BUCKET_BLOCKS;  // 2345
constexpr int ZERO_INT4     = (2 * N_NODES * CSTRIDE) / 4;   // 400000 int4
constexpr int ZERO_BLOCKS   = (ZERO_INT4 + 255) / 256;       // 1563

typedef __attribute__((ext_vector_type(8))) short bf16x8;
typedef __attribute__((ext_vector_type(4))) float f32x4;

__device__ inline short to_bf16(float f) {
    unsigned u = __builtin_bit_cast(unsigned, f);
    u += 0x7FFFu + ((u >> 16) & 1u);   // RNE; inputs are finite
    return (short)(u >> 16);
}
__device__ inline float bf16f(short h) {
    return __builtin_bit_cast(float, (unsigned)(unsigned short)h << 16);
}

// Fragment-order packed index (ROUND-9 WIN): element (col n, k) lives at
//   pos = ((ct*4 + t)*64 + lane)*8 + j
// with ct=n>>4, m=n&15, t=k>>5, quad=(k&31)>>3, j=k&7, lane=quad*16+m.
// xform's per-lane bf16x8 read of (ct,t) is base+((ct*4+t)*64+lane)*16:
// consecutive lanes -> consecutive 16B -> one 1KB transaction per load inst.
__device__ inline int frag_pos(int n, int k) {
    const int ct = n >> 4, m = n & 15;
    const int t = k >> 5, quad = (k & 31) >> 3, j = k & 7;
    return (((ct * 4 + t) * 64) + quad * 16 + m) * 8 + j;
}

// ---------------------------------------------------------------------------
// Prep kernel (also zeroes the counter arrays -> no separate memset).
//   blocks [0,32):      Wq x RFq fold -> split-bf16 FRAGMENT-PACKED WqHp/WqLp
//   blocks [32,64):     Wk x RF fold  -> WkHp/WkLp
//   blocks [64,192):    WvP[frag_pos(n,k)] = bf16(Wv[k][n])
//   blocks [192,1755):  zero srcCnt/dstCnt (1.6M ints padded, int4 stores)
// ---------------------------------------------------------------------------
__global__ __launch_bounds__(256) void prep_kernel(
    const float* __restrict__ Wq, const float* __restrict__ Wk,
    const float* __restrict__ Wv, const float* __restrict__ RF,
    const float* __restrict__ RFq,
    unsigned short* __restrict__ WqHp, unsigned short* __restrict__ WqLp,
    unsigned short* __restrict__ WkHp, unsigned short* __restrict__ WkLp,
    unsigned short* __restrict__ WvP, int* __restrict__ cnts)
{
    const int b = blockIdx.x;
    const int t = threadIdx.x;
    if (b < 64) {
        const bool isQ = (b < 32);
        const int idx = (isQ ? b : b - 32) * 256 + t;   // 0..8191
        const int d = idx >> 6;       // k index 0..127
        const int c = idx & 63;       // col 0..63
        const int hj = c >> 3, m = c & 7;
        const float* W = isQ ? Wq : Wk;
        const float* R = isQ ? RFq : RF;
        float acc = 0.f;
        #pragma unroll
        for (int dd = 0; dd < D_HEAD; ++dd)
            acc = fmaf(W[d * HD + hj * D_HEAD + dd], R[dd * M_FEAT + m], acc);
        const short h = to_bf16(acc);
        const short l = to_bf16(acc - bf16f(h));
        const int pos = frag_pos(c, d);
        (isQ ? WqHp : WkHp)[pos] = (unsigned short)h;
        (isQ ? WqLp : WkLp)[pos] = (unsigned short)l;
    } else if (b < 192) {
        const int idx = (b - 64) * 256 + t;             // 0..32767
        const int n = idx >> 7;       // col 0..255
        const int d = idx & 127;      // k 0..127
        WvP[frag_pos(n, d)] = (unsigned short)to_bf16(Wv[d * HD + n]);
    } else {
        const int idx = (b - 192) * 256 + t;            // int4 index
        if (idx < ZERO_INT4)
            ((int4*)cnts)[idx] = make_int4(0, 0, 0, 0);
    }
}

// ---------------------------------------------------------------------------
// Fused main kernel: heterogeneous grid, xform first (LPT packing).
// ROUND-7 LESSON: splitting bucket/xform cost +35us — fused bucket waves are
// the TLP hiding xform latency. Fusion is load-bearing; do not re-split.
//   blocks [0,782):      xform — 64-row block, ONE WAVE PER 16-ROW TILE
//                        (round-5 win) with fragment-packed coalesced B loads
//                        (round-9 win). ROUND-8 LESSON: no arrays through
//                        lambda pointers (scratch spill).
//   blocks [782,2345):   bucket — 1 edge/thread (round-6 lesson: batching
//                        cut concurrency 4x, +8us). ROUND-10 WIN: counters
//                        padded one per 64B line. ROUND-0 PROVEN atomic
//                        scheme: one int atomic per side, u16 src entries,
//                        u32 dst entry = src|sign<<31. ROUND-3 LESSON:
//                        packed-u32 dstCnt + pointer-select stores flaked
//                        under graph replay — do not revive.
// __launch_bounds__(256,4): ROUND-2 LESSON: (256,8) halved the reg cap ->
// full spill, FETCH 16->117MB, WRITE 77->301MB, dur 106->190us.
// Fragment maps (verified): A[m=lane&15][k=quad*8+j],
// B[k=quad*8+j][n=lane&15] (col-major, k-contig), C col=lane&15 row=quad*4+r.
// ---------------------------------------------------------------------------
__global__ __launch_bounds__(256, 4) void main_kernel(
    const int* __restrict__ src, const int* __restrict__ dst,
    const int* __restrict__ sign,
    int* __restrict__ srcCnt, unsigned short* __restrict__ srcBucket,
    int* __restrict__ dstCnt, unsigned* __restrict__ dstBucket,
    const float* __restrict__ x, const unsigned short* __restrict__ WvP,
    const unsigned short* __restrict__ WqHp, const unsigned short* __restrict__ WqLp,
    const unsigned short* __restrict__ WkHp, const unsigned short* __restrict__ WkLp,
    unsigned short* __restrict__ Vb, float* __restrict__ Sq, float* __restrict__ Phi)
{
    if (blockIdx.x >= XFORM_BLOCKS) {
        const int e = (blockIdx.x - XFORM_BLOCKS) * 256 + threadIdx.x;
        if (e >= E_EDGES) return;
        const int s = src[e];
        const int d = dst[e];
        const unsigned sb = (sign[e] == 1) ? 0x80000000u : 0u;
        // Both atomics issued before either result is consumed (round-trips overlap).
        const int ss = atomicAdd(&srcCnt[(size_t)s * CSTRIDE], 1);
        const int ds = atomicAdd(&dstCnt[(size_t)d * CSTRIDE], 1);
        if (ss < CAP) srcBucket[(size_t)s * CAP + ss] = (unsigned short)d;
        if (ds < CAP) dstBucket[(size_t)d * CAP + ds] = (unsigned)s | sb;
        return;
    }

    const int w    = threadIdx.x >> 6;   // wave id 0..3 = row-tile within block
    const int lane = threadIdx.x & 63;
    const int r0   = blockIdx.x * 64 + w * 16;   // this wave's 16-row tile
    if (r0 >= N_NODES) return;                   // only tail waves of last block
    const int m    = lane & 15;
    const int quad = lane >> 4;

    // A fragments, split hi/lo (K=128 -> 4 k-steps). Loaded ONCE per tile.
    bf16x8 Ah[4], Al[4];
    const float* xrow = x + (size_t)(r0 + m) * IN_DIM;
    #pragma unroll
    for (int t = 0; t < 4; ++t) {
        const float4 a = *(const float4*)(xrow + t * 32 + quad * 8);
        const float4 b = *(const float4*)(xrow + t * 32 + quad * 8 + 4);
        float vals[8] = {a.x, a.y, a.z, a.w, b.x, b.y, b.z, b.w};
        bf16x8 fh, fl;
        #pragma unroll
        for (int e = 0; e < 8; ++e) {
            const short hh = to_bf16(vals[e]);
            fh[e] = hh;
            fl[e] = to_bf16(vals[e] - bf16f(hh));
        }
        Ah[t] = fh; Al[t] = fl;
    }

    // Per-lane base into the fragment-packed streams (16B per (ct,t) step).
    const unsigned short* vbase = WvP + (size_t)lane * 8;
    const unsigned short* qh   = WqHp + (size_t)lane * 8;
    const unsigned short* ql   = WqLp + (size_t)lane * 8;
    const unsigned short* kh   = WkHp + (size_t)lane * 8;
    const unsigned short* kl   = WkLp + (size_t)lane * 8;

    // ---- V = x @ Wv: ALL 16 col-tiles, 4 groups of 4 (round-5 form) ----
    #pragma unroll 1
    for (int g = 0; g < 4; ++g) {
        #pragma unroll
        for (int ii = 0; ii < 2; ++ii) {
            bf16x8 Bv[8];
            #pragma unroll
            for (int i = 0; i < 2; ++i) {
                const int ct = g * 4 + ii * 2 + i;
                #pragma unroll
                for (int t = 0; t < 4; ++t)
                    Bv[i * 4 + t] = *(const bf16x8*)(vbase + (size_t)(ct * 4 + t) * 64 * 8);
            }
            #pragma unroll
            for (int i = 0; i < 2; ++i) {
                const int ct = g * 4 + ii * 2 + i;
                f32x4 acc = {0.f, 0.f, 0.f, 0.f};
                #pragma unroll
                for (int t = 0; t < 4; ++t)
                    acc = __builtin_amdgcn_mfma_f32_16x16x32_bf16(Ah[t], Bv[i * 4 + t], acc, 0, 0, 0);
                #pragma unroll
                for (int r = 0; r < 4; ++r)
                    Vb[(size_t)(r0 + quad * 4 + r) * HD + ct * 16 + m] =
                        (unsigned short)to_bf16(acc[r]);
            }
        }
    }

    // ---- q-path: ALL 4 col-tiles (pair precision), then Sq ----
    #pragma unroll 1
    for (int ct = 0; ct < 4; ++ct) {
        bf16x8 Bh[4], Bl[4];
        #pragma unroll
        for (int t = 0; t < 4; ++t) {
            Bh[t] = *(const bf16x8*)(qh + (size_t)(ct * 4 + t) * 64 * 8);
            Bl[t] = *(const bf16x8*)(ql + (size_t)(ct * 4 + t) * 64 * 8);
        }
        f32x4 acc1 = {0.f, 0.f, 0.f, 0.f};
        f32x4 acc2 = {0.f, 0.f, 0.f, 0.f};
        #pragma unroll
        for (int t = 0; t < 4; ++t) {
            acc1 = __builtin_amdgcn_mfma_f32_16x16x32_bf16(Ah[t], Bh[t], acc1, 0, 0, 0);
            acc2 = __builtin_amdgcn_mfma_f32_16x16x32_bf16(Al[t], Bh[t], acc2, 0, 0, 0);
        }
        #pragma unroll
        for (int t = 0; t < 4; ++t)
            acc1 = __builtin_amdgcn_mfma_f32_16x16x32_bf16(Ah[t], Bl[t], acc1, 0, 0, 0);
        #pragma unroll
        for (int r = 0; r < 4; ++r) {
            const float pv = acc1[r] + acc2[r];
            float tv = __cosf(pv) + __sinf(pv);
            tv += __shfl_xor(tv, 1);
            tv += __shfl_xor(tv, 2);
            tv += __shfl_xor(tv, 4);
            if ((lane & 7) == 0) {
                const int h = ct * 2 + (m >> 3);
                Sq[(r0 + quad * 4 + r) * H_HEADS + h] = tv;
            }
        }
    }

    // ---- k-path: ALL 4 col-tiles, Phi for rows < 6250 (wave-uniform skip) ----
    if (r0 < K_NODES) {
        #pragma unroll 1
        for (int ct = 0; ct < 4; ++ct) {
            const int c = ct * 16 + m;
            bf16x8 Bh[4], Bl[4];
            #pragma unroll
            for (int t = 0; t < 4; ++t) {
                Bh[t] = *(const bf16x8*)(kh + (size_t)(ct * 4 + t) * 64 * 8);
                Bl[t] = *(const bf16x8*)(kl + (size_t)(ct * 4 + t) * 64 * 8);
            }
            f32x4 acc1 = {0.f, 0.f, 0.f, 0.f};
            f32x4 acc2 = {0.f, 0.f, 0.f, 0.f};
            #pragma unroll
            for (int t = 0; t < 4; ++t) {
                acc1 = __builtin_amdgcn_mfma_f32_16x16x32_bf16(Ah[t], Bh[t], acc1, 0, 0, 0);
                acc2 = __builtin_amdgcn_mfma_f32_16x16x32_bf16(Al[t], Bh[t], acc2, 0, 0, 0);
            }
            #pragma unroll
            for (int t = 0; t < 4; ++t)
                acc1 = __builtin_amdgcn_mfma_f32_16x16x32_bf16(Ah[t], Bl[t], acc1, 0, 0, 0);
            #pragma unroll
            for (int r = 0; r < 4; ++r) {
                const int row = r0 + quad * 4 + r;
                if (row < K_NODES) {
                    const float pv = acc1[r] + acc2[r];
                    Phi[(size_t)row * 64 + c] = __cosf(pv) + __sinf(pv);
                }
            }
        }
    }
}

// ---------------------------------------------------------------------------
// Build packed PK[N][16] rows: interleaved float2 {pos,neg} per head, each
// pre-divided by max(cnt,1) -> accum does ONE float2 load per (edge,head).
// Round-0 proven gather pattern: counts derived from stored entries' sign
// bits (consistent with the sums by construction).
// Phi flat index for flat row s = n*8+j, feature m:  s*8+m == n*64 + j*8 + m.
// ---------------------------------------------------------------------------
__global__ __launch_bounds__(256) void pk_kernel(
    const int* __restrict__ dstCnt, const unsigned* __restrict__ dstBucket,
    const float* __restrict__ Phi, float* __restrict__ PK)
{
    const int t = blockIdx.x * 256 + threadIdx.x;
    if (t >= N_NODES * H_HEADS) return;
    const int d = t >> 3;
    const int h = t & 7;
    int deg = dstCnt[(size_t)d * CSTRIDE];
    if (deg > CAP) deg = CAP;

    float accp = 0.f, accn = 0.f;
    int cp = 0, cn = 0;
    for (int i = 0; i < deg; ++i) {
        const unsigned entry = dstBucket[(size_t)d * CAP + i];
        const float phi = Phi[(int)(entry & 0x7FFFFFFFu) * H_HEADS + h];
        if (entry & 0x80000000u) { accp += phi; ++cp; }
        else                     { accn += phi; ++cn; }
    }
    float2 pn;
    pn.x = accp / fmaxf((float)cp, 1.0f);
    pn.y = accn / fmaxf((float)cn, 1.0f);
    ((float2*)PK)[d * 8 + h] = pn;
}

// ---------------------------------------------------------------------------
// Gather-accumulate. One wave per src node. ROUND 11: softmax WITHOUT
// max-subtraction — |phi|<=sqrt2 so |pk|<=sqrt2 (mean), |Sq|<=8*sqrt2, so
// |np|<=16 and exp(np)<=8.9e6: fp32-safe, mathematically identical. Removes
// 12 shfl AND the serial max->exp dependency (~450cy/batch). dd broadcasts
// replaced by wave-UNIFORM scalar srcBucket reads (s_load, no DS ops).
// DS ops per batch: 40 -> 14. V gather unchanged (8 rows in flight).
// ---------------------------------------------------------------------------
__global__ __launch_bounds__(256) void accum_kernel(
    const int* __restrict__ srcCnt, const unsigned short* __restrict__ srcBucket,
    const float* __restrict__ Sq, const float* __restrict__ PK,
    const unsigned short* __restrict__ Vb, float* __restrict__ out)
{
    const int s = blockIdx.x * 4 + (threadIdx.x >> 6);
    const int lane = threadIdx.x & 63;
    const int j = lane >> 3;       // edge slot within batch
    const int h = lane & 7;        // head for attn compute
    const int myhead = lane >> 3;  // head of my output columns (c=4*lane)

    int deg = srcCnt[(size_t)s * CSTRIDE];
    if (deg > CAP) deg = CAP;
    const float sq = Sq[s * H_HEADS + h];

    float4 acc = make_float4(0.f, 0.f, 0.f, 0.f);
    const ushort4* __restrict__ V4 = (const ushort4*)Vb;   // 64 ushort4 per row
    const float2* __restrict__ PK2 = (const float2*)PK;    // 8 float2 per row

    for (int base = 0; base < deg; base += 8) {
        const int idx = base + j;
        const bool act = (idx < deg);
        const int dj = act ? (int)srcBucket[(size_t)s * CAP + idx] : 0;

        const float2 pn = PK2[dj * 8 + h];           // pk already /max(deg,1)
        const float np = sq * pn.x;
        const float nn = sq * pn.y;

        // No max-sub: |np|<=16, exp bounded by 8.9e6 (see header comment).
        const float ep = __expf(np), en = __expf(nn);
        float sp = ep, sn = en;
        sp += __shfl_xor(sp, 1); sn += __shfl_xor(sn, 1);
        sp += __shfl_xor(sp, 2); sn += __shfl_xor(sn, 2);
        sp += __shfl_xor(sp, 4); sn += __shfl_xor(sn, 4);
        float a = ep / sp - en / sn;
        if (!act) a = 0.f;

        float av[8];
        #pragma unroll
        for (int jj = 0; jj < 8; ++jj)
            av[jj] = __shfl(a, jj * 8 + myhead);

        // dd via wave-uniform scalar loads (s, base, jj all uniform -> s_load;
        // predicated by uniform base+jj<deg so no garbage-slot reads).
        ushort4 vv[8];
        #pragma unroll
        for (int jj = 0; jj < 8; ++jj) {
            const int ddj = (base + jj < deg)
                          ? (int)srcBucket[(size_t)s * CAP + base + jj] : 0;
            vv[jj] = V4[ddj * 64 + lane];            // 8 loads in flight
        }
        #pragma unroll
        for (int jj = 0; jj < 8; ++jj) {
            acc.x = fmaf(bf16f((short)vv[jj].x), av[jj], acc.x);
            acc.y = fmaf(bf16f((short)vv[jj].y), av[jj], acc.y);
            acc.z = fmaf(bf16f((short)vv[jj].z), av[jj], acc.z);
            acc.w = fmaf(bf16f((short)vv[jj].w), av[jj], acc.w);
        }
    }
    ((float4*)out)[s * 64 + lane] = acc;   // every node written -> no memset
}

extern "C" void kernel_launch(void* const* d_in, const int* in_sizes, int n_in,
                              void* d_out, int out_size, void* d_ws, size_t ws_size,
                              hipStream_t stream) {
    const float* x   = (const float*)d_in[0];
    const float* Wq  = (const float*)d_in[1];
    const float* Wk  = (const float*)d_in[2];
    const float* Wv  = (const float*)d_in[3];
    const float* RF  = (const float*)d_in[4];
    const float* RFq = (const float*)d_in[5];
    const int* eidx  = (const int*)d_in[6];
    const int* esign = (const int*)d_in[7];
    const int* src = eidx;            // edge_index[0, :]
    const int* dst = eidx + E_EDGES;  // edge_index[1, :]
    float* out = (float*)d_out;

    // Workspace layout (floats unless noted):
    //   Vb (N*256 bf16) | Sq (N*8) | Phi (6250*64) | PK (N*16) |
    //   srcCnt (N*16 int, padded), dstCnt (N*16 int, padded) |
    //   srcBucket (N*48 u16) | dstBucket (N*48 u32, sign bit 31) |
    //   fragment-packed bf16 weights                      (~53 MB total)
    float* ws      = (float*)d_ws;
    unsigned short* Vb = (unsigned short*)ws;             // N*HD bf16 = 25.6MB
    float* Sq      = ws + (size_t)N_NODES * HD / 2;       // N*8
    float* Phi     = Sq + (size_t)N_NODES * H_HEADS;      // 400000
    float* PK      = Phi + (size_t)K_NODES * 64;          // N*16 (64B rows)
    int* srcCnt    = (int*)(PK + (size_t)N_NODES * 16);   // N*16 (padded)
    int* dstCnt    = srcCnt + (size_t)N_NODES * CSTRIDE;  // N*16 (padded)
    unsigned short* srcBucket = (unsigned short*)(dstCnt + (size_t)N_NODES * CSTRIDE);
    unsigned* dstBucket = (unsigned*)(srcBucket + (size_t)N_NODES * CAP); // N*48 u32
    unsigned short* WqHp = (unsigned short*)(dstBucket + (size_t)N_NODES * CAP);
    unsigned short* WqLp = WqHp + 64 * IN_DIM;            // 8192 each
    unsigned short* WkHp = WqLp + 64 * IN_DIM;
    unsigned short* WkLp = WkHp + 64 * IN_DIM;
    unsigned short* WvP  = WkLp + 64 * IN_DIM;            // 256*128

    prep_kernel<<<192 + ZERO_BLOCKS, 256, 0, stream>>>(
        Wq, Wk, Wv, RF, RFq, WqHp, WqLp, WkHp, WkLp, WvP, srcCnt);
    main_kernel<<<MAIN_BLOCKS, 256, 0, stream>>>(
        src, dst, esign, srcCnt, srcBucket, dstCnt, dstBucket,
        x, WvP, WqHp, WqLp, WkHp, WkLp, Vb, Sq, Phi);
    pk_kernel<<<(N_NODES * H_HEADS + 255) / 256, 256, 0, stream>>>(
        dstCnt, dstBucket, Phi, PK);
    accum_kernel<<<N_NODES / 4, 256, 0, stream>>>(
        srcCnt, srcBucket, Sq, PK, Vb, out);
}

// Round 12
// 185.124 us; speedup vs baseline: 1.0912x; 1.0912x over previous
//
#include <hip/hip_runtime.h>

// Problem constants (fixed by the reference)
constexpr int N_NODES = 50000;
constexpr int E_EDGES = 400000;
constexpr int IN_DIM  = 128;
constexpr int HD      = 256;   // H*D
constexpr int H_HEADS = 8;
constexpr int D_HEAD  = 32;
constexpr int M_FEAT  = 8;
constexpr int K_NODES = N_NODES / H_HEADS;   // 6250 nodes need Phi
constexpr int CAP     = 48;    // bucket capacity; deg ~ Poisson(8), P(>=48) ~ 1e-23
constexpr int CSTRIDE = 16;    // ROUND-10 WIN: one counter per 64B line (main 71->55us;
                               // 16/line had ~128 serialized cross-XCD RMWs per hot line)
constexpr int BUCKET_BLOCKS = (E_EDGES + 255) / 256;   // 1563 (1 edge/thread)
constexpr int XFORM_BLOCKS  = (N_NODES + 63) / 64;     // 782 (64-row blocks)
constexpr int MAIN_BLOCKS   = XFORM_BLOCKS + BUCKET_BLOCKS;  // 2345
constexpr int ZERO_INT4     = (2 * N_NODES * CSTRIDE) / 4;   // 400000 int4
constexpr int ZERO_BLOCKS   = (ZERO_INT4 + 255) / 256;       // 1563

typedef __attribute__((ext_vector_type(8))) short bf16x8;
typedef __attribute__((ext_vector_type(4))) float f32x4;

__device__ inline short to_bf16(float f) {
    unsigned u = __builtin_bit_cast(unsigned, f);
    u += 0x7FFFu + ((u >> 16) & 1u);   // RNE; inputs are finite
    return (short)(u >> 16);
}
__device__ inline float bf16f(short h) {
    return __builtin_bit_cast(float, (unsigned)(unsigned short)h << 16);
}

// Fragment-order packed index (ROUND-9 WIN): element (col n, k) lives at
//   pos = ((ct*4 + t)*64 + lane)*8 + j
// with ct=n>>4, m=n&15, t=k>>5, quad=(k&31)>>3, j=k&7, lane=quad*16+m.
// xform's per-lane bf16x8 read of (ct,t) is base+((ct*4+t)*64+lane)*16:
// consecutive lanes -> consecutive 16B -> one 1KB transaction per load inst.
__device__ inline int frag_pos(int n, int k) {
    const int ct = n >> 4, m = n & 15;
    const int t = k >> 5, quad = (k & 31) >> 3, j = k & 7;
    return (((ct * 4 + t) * 64) + quad * 16 + m) * 8 + j;
}

// ---------------------------------------------------------------------------
// Prep kernel (also zeroes the counter arrays -> no separate memset).
//   blocks [0,32):      Wq x RFq fold -> split-bf16 FRAGMENT-PACKED WqHp/WqLp
//   blocks [32,64):     Wk x RF fold  -> WkHp/WkLp
//   blocks [64,192):    WvP[frag_pos(n,k)] = bf16(Wv[k][n])
//   blocks [192,1755):  zero srcCnt/dstCnt (1.6M ints padded, int4 stores)
// ---------------------------------------------------------------------------
__global__ __launch_bounds__(256) void prep_kernel(
    const float* __restrict__ Wq, const float* __restrict__ Wk,
    const float* __restrict__ Wv, const float* __restrict__ RF,
    const float* __restrict__ RFq,
    unsigned short* __restrict__ WqHp, unsigned short* __restrict__ WqLp,
    unsigned short* __restrict__ WkHp, unsigned short* __restrict__ WkLp,
    unsigned short* __restrict__ WvP, int* __restrict__ cnts)
{
    const int b = blockIdx.x;
    const int t = threadIdx.x;
    if (b < 64) {
        const bool isQ = (b < 32);
        const int idx = (isQ ? b : b - 32) * 256 + t;   // 0..8191
        const int d = idx >> 6;       // k index 0..127
        const int c = idx & 63;       // col 0..63
        const int hj = c >> 3, m = c & 7;
        const float* W = isQ ? Wq : Wk;
        const float* R = isQ ? RFq : RF;
        float acc = 0.f;
        #pragma unroll
        for (int dd = 0; dd < D_HEAD; ++dd)
            acc = fmaf(W[d * HD + hj * D_HEAD + dd], R[dd * M_FEAT + m], acc);
        const short h = to_bf16(acc);
        const short l = to_bf16(acc - bf16f(h));
        const int pos = frag_pos(c, d);
        (isQ ? WqHp : WkHp)[pos] = (unsigned short)h;
        (isQ ? WqLp : WkLp)[pos] = (unsigned short)l;
    } else if (b < 192) {
        const int idx = (b - 64) * 256 + t;             // 0..32767
        const int n = idx >> 7;       // col 0..255
        const int d = idx & 127;      // k 0..127
        WvP[frag_pos(n, d)] = (unsigned short)to_bf16(Wv[d * HD + n]);
    } else {
        const int idx = (b - 192) * 256 + t;            // int4 index
        if (idx < ZERO_INT4)
            ((int4*)cnts)[idx] = make_int4(0, 0, 0, 0);
    }
}

// ---------------------------------------------------------------------------
// Fused main kernel: heterogeneous grid, xform first (LPT packing).
// ROUND-7 LESSON: splitting bucket/xform cost +35us — fused bucket waves are
// the TLP hiding xform latency. Fusion is load-bearing; do not re-split.
//   blocks [0,782):      xform — 64-row block, ONE WAVE PER 16-ROW TILE
//                        (round-5 win) with fragment-packed coalesced B loads
//                        (round-9 win). ROUND-8 LESSON: no arrays through
//                        lambda pointers (scratch spill).
//   blocks [782,2345):   bucket — 1 edge/thread (round-6 lesson: batching
//                        cut concurrency 4x, +8us). ROUND-10 WIN: counters
//                        padded one per 64B line. ROUND-0 PROVEN atomic
//                        scheme: one int atomic per side, u16 src entries,
//                        u32 dst entry = src|sign<<31. ROUND-3 LESSON:
//                        packed-u32 dstCnt + pointer-select stores flaked
//                        under graph replay — do not revive.
// __launch_bounds__(256,4): ROUND-2 LESSON: (256,8) halved the reg cap ->
// full spill, FETCH 16->117MB, WRITE 77->301MB, dur 106->190us.
// Fragment maps (verified): A[m=lane&15][k=quad*8+j],
// B[k=quad*8+j][n=lane&15] (col-major, k-contig), C col=lane&15 row=quad*4+r.
// ---------------------------------------------------------------------------
__global__ __launch_bounds__(256, 4) void main_kernel(
    const int* __restrict__ src, const int* __restrict__ dst,
    const int* __restrict__ sign,
    int* __restrict__ srcCnt, unsigned short* __restrict__ srcBucket,
    int* __restrict__ dstCnt, unsigned* __restrict__ dstBucket,
    const float* __restrict__ x, const unsigned short* __restrict__ WvP,
    const unsigned short* __restrict__ WqHp, const unsigned short* __restrict__ WqLp,
    const unsigned short* __restrict__ WkHp, const unsigned short* __restrict__ WkLp,
    unsigned short* __restrict__ Vb, float* __restrict__ Sq, float* __restrict__ Phi)
{
    if (blockIdx.x >= XFORM_BLOCKS) {
        const int e = (blockIdx.x - XFORM_BLOCKS) * 256 + threadIdx.x;
        if (e >= E_EDGES) return;
        const int s = src[e];
        const int d = dst[e];
        const unsigned sb = (sign[e] == 1) ? 0x80000000u : 0u;
        // Both atomics issued before either result is consumed (round-trips overlap).
        const int ss = atomicAdd(&srcCnt[(size_t)s * CSTRIDE], 1);
        const int ds = atomicAdd(&dstCnt[(size_t)d * CSTRIDE], 1);
        if (ss < CAP) srcBucket[(size_t)s * CAP + ss] = (unsigned short)d;
        if (ds < CAP) dstBucket[(size_t)d * CAP + ds] = (unsigned)s | sb;
        return;
    }

    const int w    = threadIdx.x >> 6;   // wave id 0..3 = row-tile within block
    const int lane = threadIdx.x & 63;
    const int r0   = blockIdx.x * 64 + w * 16;   // this wave's 16-row tile
    if (r0 >= N_NODES) return;                   // only tail waves of last block
    const int m    = lane & 15;
    const int quad = lane >> 4;

    // A fragments, split hi/lo (K=128 -> 4 k-steps). Loaded ONCE per tile.
    bf16x8 Ah[4], Al[4];
    const float* xrow = x + (size_t)(r0 + m) * IN_DIM;
    #pragma unroll
    for (int t = 0; t < 4; ++t) {
        const float4 a = *(const float4*)(xrow + t * 32 + quad * 8);
        const float4 b = *(const float4*)(xrow + t * 32 + quad * 8 + 4);
        float vals[8] = {a.x, a.y, a.z, a.w, b.x, b.y, b.z, b.w};
        bf16x8 fh, fl;
        #pragma unroll
        for (int e = 0; e < 8; ++e) {
            const short hh = to_bf16(vals[e]);
            fh[e] = hh;
            fl[e] = to_bf16(vals[e] - bf16f(hh));
        }
        Ah[t] = fh; Al[t] = fl;
    }

    // Per-lane base into the fragment-packed streams (16B per (ct,t) step).
    const unsigned short* vbase = WvP + (size_t)lane * 8;
    const unsigned short* qh   = WqHp + (size_t)lane * 8;
    const unsigned short* ql   = WqLp + (size_t)lane * 8;
    const unsigned short* kh   = WkHp + (size_t)lane * 8;
    const unsigned short* kl   = WkLp + (size_t)lane * 8;

    // ---- V = x @ Wv: ALL 16 col-tiles, 4 groups of 4 (round-5 form) ----
    #pragma unroll 1
    for (int g = 0; g < 4; ++g) {
        #pragma unroll
        for (int ii = 0; ii < 2; ++ii) {
            bf16x8 Bv[8];
            #pragma unroll
            for (int i = 0; i < 2; ++i) {
                const int ct = g * 4 + ii * 2 + i;
                #pragma unroll
                for (int t = 0; t < 4; ++t)
                    Bv[i * 4 + t] = *(const bf16x8*)(vbase + (size_t)(ct * 4 + t) * 64 * 8);
            }
            #pragma unroll
            for (int i = 0; i < 2; ++i) {
                const int ct = g * 4 + ii * 2 + i;
                f32x4 acc = {0.f, 0.f, 0.f, 0.f};
                #pragma unroll
                for (int t = 0; t < 4; ++t)
                    acc = __builtin_amdgcn_mfma_f32_16x16x32_bf16(Ah[t], Bv[i * 4 + t], acc, 0, 0, 0);
                #pragma unroll
                for (int r = 0; r < 4; ++r)
                    Vb[(size_t)(r0 + quad * 4 + r) * HD + ct * 16 + m] =
                        (unsigned short)to_bf16(acc[r]);
            }
        }
    }

    // ---- q-path: ALL 4 col-tiles (pair precision), then Sq ----
    #pragma unroll 1
    for (int ct = 0; ct < 4; ++ct) {
        bf16x8 Bh[4], Bl[4];
        #pragma unroll
        for (int t = 0; t < 4; ++t) {
            Bh[t] = *(const bf16x8*)(qh + (size_t)(ct * 4 + t) * 64 * 8);
            Bl[t] = *(const bf16x8*)(ql + (size_t)(ct * 4 + t) * 64 * 8);
        }
        f32x4 acc1 = {0.f, 0.f, 0.f, 0.f};
        f32x4 acc2 = {0.f, 0.f, 0.f, 0.f};
        #pragma unroll
        for (int t = 0; t < 4; ++t) {
            acc1 = __builtin_amdgcn_mfma_f32_16x16x32_bf16(Ah[t], Bh[t], acc1, 0, 0, 0);
            acc2 = __builtin_amdgcn_mfma_f32_16x16x32_bf16(Al[t], Bh[t], acc2, 0, 0, 0);
        }
        #pragma unroll
        for (int t = 0; t < 4; ++t)
            acc1 = __builtin_amdgcn_mfma_f32_16x16x32_bf16(Ah[t], Bl[t], acc1, 0, 0, 0);
        #pragma unroll
        for (int r = 0; r < 4; ++r) {
            const float pv = acc1[r] + acc2[r];
            float tv = __cosf(pv) + __sinf(pv);
            tv += __shfl_xor(tv, 1);
            tv += __shfl_xor(tv, 2);
            tv += __shfl_xor(tv, 4);
            if ((lane & 7) == 0) {
                const int h = ct * 2 + (m >> 3);
                Sq[(r0 + quad * 4 + r) * H_HEADS + h] = tv;
            }
        }
    }

    // ---- k-path: ALL 4 col-tiles, Phi for rows < 6250 (wave-uniform skip) ----
    if (r0 < K_NODES) {
        #pragma unroll 1
        for (int ct = 0; ct < 4; ++ct) {
            const int c = ct * 16 + m;
            bf16x8 Bh[4], Bl[4];
            #pragma unroll
            for (int t = 0; t < 4; ++t) {
                Bh[t] = *(const bf16x8*)(kh + (size_t)(ct * 4 + t) * 64 * 8);
                Bl[t] = *(const bf16x8*)(kl + (size_t)(ct * 4 + t) * 64 * 8);
            }
            f32x4 acc1 = {0.f, 0.f, 0.f, 0.f};
            f32x4 acc2 = {0.f, 0.f, 0.f, 0.f};
            #pragma unroll
            for (int t = 0; t < 4; ++t) {
                acc1 = __builtin_amdgcn_mfma_f32_16x16x32_bf16(Ah[t], Bh[t], acc1, 0, 0, 0);
                acc2 = __builtin_amdgcn_mfma_f32_16x16x32_bf16(Al[t], Bh[t], acc2, 0, 0, 0);
            }
            #pragma unroll
            for (int t = 0; t < 4; ++t)
                acc1 = __builtin_amdgcn_mfma_f32_16x16x32_bf16(Ah[t], Bl[t], acc1, 0, 0, 0);
            #pragma unroll
            for (int r = 0; r < 4; ++r) {
                const int row = r0 + quad * 4 + r;
                if (row < K_NODES) {
                    const float pv = acc1[r] + acc2[r];
                    Phi[(size_t)row * 64 + c] = __cosf(pv) + __sinf(pv);
                }
            }
        }
    }
}

// ---------------------------------------------------------------------------
// Build packed PK[N][16] rows: interleaved float2 {pos,neg} per head, each
// pre-divided by max(cnt,1) -> accum does ONE float2 load per (edge,head).
// Round-0 proven gather pattern: counts derived from stored entries' sign
// bits (consistent with the sums by construction).
// Phi flat index for flat row s = n*8+j, feature m:  s*8+m == n*64 + j*8 + m.
// ---------------------------------------------------------------------------
__global__ __launch_bounds__(256) void pk_kernel(
    const int* __restrict__ dstCnt, const unsigned* __restrict__ dstBucket,
    const float* __restrict__ Phi, float* __restrict__ PK)
{
    const int t = blockIdx.x * 256 + threadIdx.x;
    if (t >= N_NODES * H_HEADS) return;
    const int d = t >> 3;
    const int h = t & 7;
    int deg = dstCnt[(size_t)d * CSTRIDE];
    if (deg > CAP) deg = CAP;

    float accp = 0.f, accn = 0.f;
    int cp = 0, cn = 0;
    for (int i = 0; i < deg; ++i) {
        const unsigned entry = dstBucket[(size_t)d * CAP + i];
        const float phi = Phi[(int)(entry & 0x7FFFFFFFu) * H_HEADS + h];
        if (entry & 0x80000000u) { accp += phi; ++cp; }
        else                     { accn += phi; ++cn; }
    }
    float2 pn;
    pn.x = accp / fmaxf((float)cp, 1.0f);
    pn.y = accn / fmaxf((float)cn, 1.0f);
    ((float2*)PK)[d * 8 + h] = pn;
}

// ---------------------------------------------------------------------------
// Gather-accumulate. One wave per src node. ROUND 12: HYBRID of the proven
// round-10 structure and round-11's safe half.
//   KEPT from round 11: softmax WITHOUT max-subtraction — |phi|<=sqrt2 so
//   |pk|<=sqrt2 (mean), |Sq|<=8*sqrt2 -> |np|<=16, exp<=8.9e6: fp32-safe and
//   mathematically identical (verified absmax 0.03125). Removes 12 shfl and
//   the serial max->exp dependency.
//   REVERTED from round 11: dd via "uniform scalar loads" — srcBucket is u16
//   and SMEM is dword-granular, so the compiler emitted 8 per-lane VMEM
//   ushort loads on the critical path (+13us total). Back to the coalesced
//   per-lane dj load + __shfl broadcasts (DS ops, ~proven in rounds 1-10).
// ---------------------------------------------------------------------------
__global__ __launch_bounds__(256) void accum_kernel(
    const int* __restrict__ srcCnt, const unsigned short* __restrict__ srcBucket,
    const float* __restrict__ Sq, const float* __restrict__ PK,
    const unsigned short* __restrict__ Vb, float* __restrict__ out)
{
    const int s = blockIdx.x * 4 + (threadIdx.x >> 6);
    const int lane = threadIdx.x & 63;
    const int j = lane >> 3;       // edge slot within batch
    const int h = lane & 7;        // head for attn compute
    const int myhead = lane >> 3;  // head of my output columns (c=4*lane)

    int deg = srcCnt[(size_t)s * CSTRIDE];
    if (deg > CAP) deg = CAP;
    const float sq = Sq[s * H_HEADS + h];

    float4 acc = make_float4(0.f, 0.f, 0.f, 0.f);
    const ushort4* __restrict__ V4 = (const ushort4*)Vb;   // 64 ushort4 per row
    const float2* __restrict__ PK2 = (const float2*)PK;    // 8 float2 per row

    for (int base = 0; base < deg; base += 8) {
        const int idx = base + j;
        const bool act = (idx < deg);
        const int dj = act ? (int)srcBucket[(size_t)s * CAP + idx] : 0;

        const float2 pn = PK2[dj * 8 + h];           // pk already /max(deg,1)
        const float np = sq * pn.x;
        const float nn = sq * pn.y;

        // No max-sub: |np|<=16, exp bounded by 8.9e6 (see header comment).
        const float ep = __expf(np), en = __expf(nn);
        float sp = ep, sn = en;
        sp += __shfl_xor(sp, 1); sn += __shfl_xor(sn, 1);
        sp += __shfl_xor(sp, 2); sn += __shfl_xor(sn, 2);
        sp += __shfl_xor(sp, 4); sn += __shfl_xor(sn, 4);
        float a = ep / sp - en / sn;
        if (!act) a = 0.f;

        int   dd[8];
        float av[8];
        #pragma unroll
        for (int jj = 0; jj < 8; ++jj) {
            dd[jj] = __shfl(dj, jj * 8);
            av[jj] = __shfl(a,  jj * 8 + myhead);
        }
        ushort4 vv[8];
        #pragma unroll
        for (int jj = 0; jj < 8; ++jj)
            vv[jj] = V4[dd[jj] * 64 + lane];         // 8 loads in flight
        #pragma unroll
        for (int jj = 0; jj < 8; ++jj) {
            acc.x = fmaf(bf16f((short)vv[jj].x), av[jj], acc.x);
            acc.y = fmaf(bf16f((short)vv[jj].y), av[jj], acc.y);
            acc.z = fmaf(bf16f((short)vv[jj].z), av[jj], acc.z);
            acc.w = fmaf(bf16f((short)vv[jj].w), av[jj], acc.w);
        }
    }
    ((float4*)out)[s * 64 + lane] = acc;   // every node written -> no memset
}

extern "C" void kernel_launch(void* const* d_in, const int* in_sizes, int n_in,
                              void* d_out, int out_size, void* d_ws, size_t ws_size,
                              hipStream_t stream) {
    const float* x   = (const float*)d_in[0];
    const float* Wq  = (const float*)d_in[1];
    const float* Wk  = (const float*)d_in[2];
    const float* Wv  = (const float*)d_in[3];
    const float* RF  = (const float*)d_in[4];
    const float* RFq = (const float*)d_in[5];
    const int* eidx  = (const int*)d_in[6];
    const int* esign = (const int*)d_in[7];
    const int* src = eidx;            // edge_index[0, :]
    const int* dst = eidx + E_EDGES;  // edge_index[1, :]
    float* out = (float*)d_out;

    // Workspace layout (floats unless noted):
    //   Vb (N*256 bf16) | Sq (N*8) | Phi (6250*64) | PK (N*16) |
    //   srcCnt (N*16 int, padded), dstCnt (N*16 int, padded) |
    //   srcBucket (N*48 u16) | dstBucket (N*48 u32, sign bit 31) |
    //   fragment-packed bf16 weights                      (~53 MB total)
    float* ws      = (float*)d_ws;
    unsigned short* Vb = (unsigned short*)ws;             // N*HD bf16 = 25.6MB
    float* Sq      = ws + (size_t)N_NODES * HD / 2;       // N*8
    float* Phi     = Sq + (size_t)N_NODES * H_HEADS;      // 400000
    float* PK      = Phi + (size_t)K_NODES * 64;          // N*16 (64B rows)
    int* srcCnt    = (int*)(PK + (size_t)N_NODES * 16);   // N*16 (padded)
    int* dstCnt    = srcCnt + (size_t)N_NODES * CSTRIDE;  // N*16 (padded)
    unsigned short* srcBucket = (unsigned short*)(dstCnt + (size_t)N_NODES * CSTRIDE);
    unsigned* dstBucket = (unsigned*)(srcBucket + (size_t)N_NODES * CAP); // N*48 u32
    unsigned short* WqHp = (unsigned short*)(dstBucket + (size_t)N_NODES * CAP);
    unsigned short* WqLp = WqHp + 64 * IN_DIM;            // 8192 each
    unsigned short* WkHp = WqLp + 64 * IN_DIM;
    unsigned short* WkLp = WkHp + 64 * IN_DIM;
    unsigned short* WvP  = WkLp + 64 * IN_DIM;            // 256*128

    prep_kernel<<<192 + ZERO_BLOCKS, 256, 0, stream>>>(
        Wq, Wk, Wv, RF, RFq, WqHp, WqLp, WkHp, WkLp, WvP, srcCnt);
    main_kernel<<<MAIN_BLOCKS, 256, 0, stream>>>(
        src, dst, esign, srcCnt, srcBucket, dstCnt, dstBucket,
        x, WvP, WqHp, WqLp, WkHp, WkLp, Vb, Sq, Phi);
    pk_kernel<<<(N_NODES * H_HEADS + 255) / 256, 256, 0, stream>>>(
        dstCnt, dstBucket, Phi, PK);
    accum_kernel<<<N_NODES / 4, 256, 0, stream>>>(
        srcCnt, srcBucket, Sq, PK, Vb, out);
}